// Round 1
// baseline (1651.055 us; speedup 1.0000x reference)
//
#include <hip/hip_runtime.h>
#include <math.h>

#define BB 512
#define DD 128
#define KK 8
#define BOUNDARY 4

// ---------------- workspace layout (bytes) ----------------
// d     : 0          .. 1048576   (512*512 float)
// sq    : 1048576    .. 1050624   (512 float)
// cnt   : 1050624    .. 1051136   (128 int)
// maskP : 1051136    .. 1313280   (512*512 u8)
// maskN : 1313280    .. 1575424   (512*512 u8)
// accum : 1575424    .. 1575432   (float sum, int count)

__global__ void sq_cnt_kernel(const float* __restrict__ x, const int* __restrict__ tgt,
                              float* __restrict__ sq, int* __restrict__ cnt) {
    int i = blockIdx.x * blockDim.x + threadIdx.x;
    if (i >= BB) return;
    const float* xi = x + i * DD;
    float s = 0.f;
    for (int c = 0; c < DD; ++c) s += xi[c] * xi[c];
    sq[i] = s;
    atomicAdd(&cnt[tgt[i]], 1);
}

__global__ void dist_kernel(const float* __restrict__ x, const float* __restrict__ sq,
                            float* __restrict__ d) {
    __shared__ float xi[DD];
    int i = blockIdx.x;
    if (threadIdx.x < DD) xi[threadIdx.x] = x[i * DD + threadIdx.x];
    __syncthreads();
    float sqi = sq[i];
    for (int j = threadIdx.x; j < BB; j += blockDim.x) {
        const float* xj = x + j * DD;
        float dot = 0.f;
        for (int c = 0; c < DD; ++c) dot += xi[c] * xj[c];
        float dsq = sqi + sq[j] - 2.f * dot;
        dsq = fmaxf(dsq, 0.f);
        d[i * BB + j] = (dsq == 0.f) ? 0.f : sqrtf(dsq);
    }
}

// Per column j: mark top-K rows. Replicates jax.lax.top_k ordering:
// descending value, ties broken toward lower index.
__global__ void topk_kernel(const float* __restrict__ d, const int* __restrict__ tgt,
                            unsigned char* __restrict__ maskP,
                            unsigned char* __restrict__ maskN) {
    int j = blockIdx.x * blockDim.x + threadIdx.x;
    if (j >= BB) return;
    int tj = tgt[j];

    // hard positives: largest same-class distances
    {
        float pv = INFINITY; int pi = -1;
        for (int pass = 0; pass < KK; ++pass) {
            float bv = -INFINITY; int bi = -1;
            for (int r = 0; r < BB; ++r) {
                float v = (tgt[r] == tj) ? d[r * BB + j] : -INFINITY;
                bool lt_prev = (v < pv) || (v == pv && r > pi);
                bool gt_best = (v > bv) || (v == bv && bi >= 0 && r < bi);
                if (lt_prev && gt_best) { bv = v; bi = r; }
            }
            if (bi < 0) break;                       // exhausted
            if (bv != -INFINITY) maskP[bi * BB + j] = 1;  // only same-class picks
            pv = bv; pi = bi;
        }
    }
    // hard negatives: smallest different-class distances (top-k of -d)
    {
        float pv = INFINITY; int pi = -1;
        for (int pass = 0; pass < KK; ++pass) {
            float bv = -INFINITY; int bi = -1;
            for (int r = 0; r < BB; ++r) {
                float v = (tgt[r] == tj) ? -INFINITY : -d[r * BB + j];
                bool lt_prev = (v < pv) || (v == pv && r > pi);
                bool gt_best = (v > bv) || (v == bv && bi >= 0 && r < bi);
                if (lt_prev && gt_best) { bv = v; bi = r; }
            }
            if (bi < 0) break;
            if (bv != -INFINITY) maskN[bi * BB + j] = 1;
            pv = bv; pi = bi;
        }
    }
}

__global__ void loss_kernel(const float* __restrict__ d, const int* __restrict__ tgt,
                            const int* __restrict__ cnt,
                            const unsigned char* __restrict__ maskP,
                            const unsigned char* __restrict__ maskN,
                            float* __restrict__ accum) {
    int i = blockIdx.x;
    if (cnt[tgt[i]] >= BOUNDARY) return;   // not a minor-class anchor
    __shared__ int pos[BB];
    __shared__ int neg[BB];
    __shared__ int np, nn;
    if (threadIdx.x == 0) { np = 0; nn = 0; }
    __syncthreads();
    for (int j = threadIdx.x; j < BB; j += blockDim.x) {
        if (j != i && maskP[i * BB + j]) pos[atomicAdd(&np, 1)] = j;
        if (maskN[i * BB + j])           neg[atomicAdd(&nn, 1)] = j;
    }
    __syncthreads();
    int npos = np, nneg = nn;
    int tot = npos * nneg;
    float s = 0.f; int c = 0;
    for (int t = threadIdx.x; t < tot; t += blockDim.x) {
        int j = pos[t / nneg];
        int k = neg[t % nneg];
        float tv = d[i * BB + j] - d[i * BB + k] + 1.0f;
        if (tv > 0.f) {
            s += tv;
            if (tv > 1e-7f) c += 1;
        }
    }
    if (s != 0.f || c != 0) {
        atomicAdd(&accum[0], s);
        atomicAdd((int*)(accum + 1), c);
    }
}

__global__ void fin_kernel(const float* __restrict__ accum, float* __restrict__ out) {
    float s = accum[0];
    int c = ((const int*)accum)[1];
    out[0] = s / ((float)c + 1e-7f);
}

extern "C" void kernel_launch(void* const* d_in, const int* in_sizes, int n_in,
                              void* d_out, int out_size, void* d_ws, size_t ws_size,
                              hipStream_t stream) {
    const float* x   = (const float*)d_in[0];
    const int*   tgt = (const int*)d_in[1];
    float* out = (float*)d_out;

    char* ws = (char*)d_ws;
    float*         dmat  = (float*)(ws + 0);
    float*         sq    = (float*)(ws + 1048576);
    int*           cnt   = (int*)(ws + 1050624);
    unsigned char* maskP = (unsigned char*)(ws + 1051136);
    unsigned char* maskN = (unsigned char*)(ws + 1313280);
    float*         accum = (float*)(ws + 1575424);

    // zero cnt + masks + accum (ws is poisoned 0xAA before every launch)
    hipMemsetAsync(ws + 1050624, 0, 1575432 - 1050624, stream);

    sq_cnt_kernel<<<2, 256, 0, stream>>>(x, tgt, sq, cnt);
    dist_kernel<<<BB, 256, 0, stream>>>(x, sq, dmat);
    topk_kernel<<<8, 64, 0, stream>>>(dmat, tgt, maskP, maskN);
    loss_kernel<<<BB, 256, 0, stream>>>(dmat, tgt, cnt, maskP, maskN, accum);
    fin_kernel<<<1, 1, 0, stream>>>(accum, out);
}

// Round 2
// 125.352 us; speedup vs baseline: 13.1714x; 13.1714x over previous
//
#include <hip/hip_runtime.h>
#include <math.h>

#define BB 512
#define DD 128
#define KK 8
#define BOUNDARY 4

// ---------------- workspace layout (bytes) ----------------
// d     : 0          .. 1048576   (512*512 float)
// sq    : 1048576    .. 1050624   (512 float)
// cnt   : 1050624    .. 1051136   (128 int)
// maskP : 1051136    .. 1313280   (512*512 u8)
// maskN : 1313280    .. 1575424   (512*512 u8)
// accum : 1575424    .. 1575432   (float sum, int count)

__global__ void sq_cnt_kernel(const float* __restrict__ x, const int* __restrict__ tgt,
                              float* __restrict__ sq, int* __restrict__ cnt) {
    int i = blockIdx.x * blockDim.x + threadIdx.x;
    if (i >= BB) return;
    const float* xi = x + i * DD;
    float s = 0.f;
    for (int c = 0; c < DD; ++c) s += xi[c] * xi[c];
    sq[i] = s;
    atomicAdd(&cnt[tgt[i]], 1);
}

__global__ void dist_kernel(const float* __restrict__ x, const float* __restrict__ sq,
                            float* __restrict__ d) {
    __shared__ float4 xi4[DD / 4];
    int i = blockIdx.x;
    if (threadIdx.x < DD / 4)
        xi4[threadIdx.x] = ((const float4*)(x + i * DD))[threadIdx.x];
    __syncthreads();
    float sqi = sq[i];
    for (int j = threadIdx.x; j < BB; j += blockDim.x) {
        const float4* xj = (const float4*)(x + j * DD);
        float dot = 0.f;
        // sequential accumulation order == scalar c-loop (bitwise identical)
        for (int c = 0; c < DD / 4; ++c) {
            float4 a = xi4[c], b = xj[c];
            dot += a.x * b.x;
            dot += a.y * b.y;
            dot += a.z * b.z;
            dot += a.w * b.w;
        }
        float dsq = sqi + sq[j] - 2.f * dot;
        dsq = fmaxf(dsq, 0.f);
        d[i * BB + j] = (dsq == 0.f) ? 0.f : sqrtf(dsq);
    }
}

// One 64-lane wave per column j. d is bitwise symmetric, so column j == row j
// (contiguous loads). Top-k set via 8 argmax-with-removal passes; ties broken
// toward lower row index, matching jax.lax.top_k.
__global__ void topk_kernel(const float* __restrict__ d, const int* __restrict__ tgt,
                            unsigned char* __restrict__ maskP,
                            unsigned char* __restrict__ maskN) {
    int j = blockIdx.x;
    int lane = threadIdx.x;           // 0..63
    int tj = tgt[j];

    float vp[8], vn[8];
    for (int q = 0; q < 8; ++q) {
        int r = q * 64 + lane;
        float dv = d[j * BB + r];     // row j == column j
        bool same = (tgt[r] == tj);
        vp[q] = same ? dv : -INFINITY;
        vn[q] = same ? -INFINITY : -dv;
    }

    // hard positives
    for (int pass = 0; pass < KK; ++pass) {
        float bv = -INFINITY; int bq = -1;
        for (int q = 0; q < 8; ++q)
            if (vp[q] > bv) { bv = vp[q]; bq = q; }
        int bi = (bq >= 0) ? (bq * 64 + lane) : (1 << 30);
        for (int off = 32; off > 0; off >>= 1) {
            float ov = __shfl_down(bv, off);
            int   oi = __shfl_down(bi, off);
            if (ov > bv || (ov == bv && oi < bi)) { bv = ov; bi = oi; }
        }
        bv = __shfl(bv, 0); bi = __shfl(bi, 0);
        if (bv == -INFINITY) break;
        if (lane == 0) maskP[bi * BB + j] = 1;
        if ((bi & 63) == lane) vp[bi >> 6] = -INFINITY;
    }
    // hard negatives (top-k of -d among different-class rows)
    for (int pass = 0; pass < KK; ++pass) {
        float bv = -INFINITY; int bq = -1;
        for (int q = 0; q < 8; ++q)
            if (vn[q] > bv) { bv = vn[q]; bq = q; }
        int bi = (bq >= 0) ? (bq * 64 + lane) : (1 << 30);
        for (int off = 32; off > 0; off >>= 1) {
            float ov = __shfl_down(bv, off);
            int   oi = __shfl_down(bi, off);
            if (ov > bv || (ov == bv && oi < bi)) { bv = ov; bi = oi; }
        }
        bv = __shfl(bv, 0); bi = __shfl(bi, 0);
        if (bv == -INFINITY) break;
        if (lane == 0) maskN[bi * BB + j] = 1;
        if ((bi & 63) == lane) vn[bi >> 6] = -INFINITY;
    }
}

__global__ void loss_kernel(const float* __restrict__ d, const int* __restrict__ tgt,
                            const int* __restrict__ cnt,
                            const unsigned char* __restrict__ maskP,
                            const unsigned char* __restrict__ maskN,
                            float* __restrict__ accum) {
    int i = blockIdx.x;
    if (cnt[tgt[i]] >= BOUNDARY) return;   // not a minor-class anchor
    __shared__ int pos[BB];
    __shared__ int neg[BB];
    __shared__ int np, nn;
    if (threadIdx.x == 0) { np = 0; nn = 0; }
    __syncthreads();
    for (int j = threadIdx.x; j < BB; j += blockDim.x) {
        if (j != i && maskP[i * BB + j]) pos[atomicAdd(&np, 1)] = j;
        if (maskN[i * BB + j])           neg[atomicAdd(&nn, 1)] = j;
    }
    __syncthreads();
    int npos = np, nneg = nn;
    int tot = npos * nneg;
    float s = 0.f; int c = 0;
    for (int t = threadIdx.x; t < tot; t += blockDim.x) {
        int j = pos[t / nneg];
        int k = neg[t % nneg];
        float tv = d[i * BB + j] - d[i * BB + k] + 1.0f;
        if (tv > 0.f) {
            s += tv;
            if (tv > 1e-7f) c += 1;
        }
    }
    if (s != 0.f || c != 0) {
        atomicAdd(&accum[0], s);
        atomicAdd((int*)(accum + 1), c);
    }
}

__global__ void fin_kernel(const float* __restrict__ accum, float* __restrict__ out) {
    float s = accum[0];
    int c = ((const int*)accum)[1];
    out[0] = s / ((float)c + 1e-7f);
}

extern "C" void kernel_launch(void* const* d_in, const int* in_sizes, int n_in,
                              void* d_out, int out_size, void* d_ws, size_t ws_size,
                              hipStream_t stream) {
    const float* x   = (const float*)d_in[0];
    const int*   tgt = (const int*)d_in[1];
    float* out = (float*)d_out;

    char* ws = (char*)d_ws;
    float*         dmat  = (float*)(ws + 0);
    float*         sq    = (float*)(ws + 1048576);
    int*           cnt   = (int*)(ws + 1050624);
    unsigned char* maskP = (unsigned char*)(ws + 1051136);
    unsigned char* maskN = (unsigned char*)(ws + 1313280);
    float*         accum = (float*)(ws + 1575424);

    // zero cnt + masks + accum (ws is poisoned 0xAA before every launch)
    hipMemsetAsync(ws + 1050624, 0, 1575432 - 1050624, stream);

    sq_cnt_kernel<<<2, 256, 0, stream>>>(x, tgt, sq, cnt);
    dist_kernel<<<BB, 256, 0, stream>>>(x, sq, dmat);
    topk_kernel<<<BB, 64, 0, stream>>>(dmat, tgt, maskP, maskN);
    loss_kernel<<<BB, 256, 0, stream>>>(dmat, tgt, cnt, maskP, maskN, accum);
    fin_kernel<<<1, 1, 0, stream>>>(accum, out);
}